// Round 13
// baseline (2006.017 us; speedup 1.0000x reference)
//
#include <hip/hip_runtime.h>
#include <hip/hip_fp8.h>
#include <cmath>

#define SS 512
#define BB 32
#define EE 128
#define HH 256
#define VV 10000
#define NROWS (SS*BB)   // 16384
#define VPAD 10048

typedef unsigned short ushort_t;
typedef unsigned char uchar_t;
typedef __attribute__((ext_vector_type(8))) short bf16x8;
typedef __attribute__((ext_vector_type(8))) int i32x8;
typedef __attribute__((ext_vector_type(4))) float f32x4;

#define MFMA(a,b,c)  __builtin_amdgcn_mfma_f32_16x16x32_bf16((a),(b),(c),0,0,0)
// fp8 x fp8, K=128, unit scales (E8M0 127 = 1.0) -> numerically plain fp8 matmul
#define MFMAS(a,b,c) __builtin_amdgcn_mfma_scale_f32_16x16x128_f8f6f4((a),(b),(c),0,0,0,0x7F7F7F7F,0,0x7F7F7F7F)

__device__ __forceinline__ ushort_t f2bf(float x) {
    unsigned u = __float_as_uint(x);
    u = (u + 0x7FFFu + ((u >> 16) & 1u)) >> 16;   // RNE
    return (ushort_t)u;
}
__device__ __forceinline__ float bf2f(ushort_t h) {
    return __uint_as_float(((unsigned)h) << 16);
}
__device__ __forceinline__ uchar_t f2fp8(float x) {
    __hip_fp8_e4m3 t(x);                           // OCP e4m3
    return (uchar_t)t.__x;
}
__device__ __forceinline__ float sigf(float x) { return 1.0f / (1.0f + __expf(-x)); }
__device__ __forceinline__ float tanhf_(float x) { return 1.0f - 2.0f / (__expf(2.0f * x) + 1.0f); }

// assemble a 32-B fp8 fragment from two 16-B halves 1024 B apart (LDS or global)
__device__ __forceinline__ i32x8 ldfrag(const uchar_t* base, int lane) {
    i32x8 r;
    ((uint4*)&r)[0] = *(const uint4*)(base + lane * 16);
    ((uint4*)&r)[1] = *(const uint4*)(base + 1024 + lane * 16);
    return r;
}

// ---------------- zgemm: layer-1 x-part (b0 folded), plain bf16 [row][1024] (R9-validated) ----
__global__ __launch_bounds__(256)
void zgemm_b(const float* __restrict__ Wk, const float* __restrict__ bias,
             const float* __restrict__ xin, const int* __restrict__ idx,
             ushort_t* __restrict__ Zb)
{
    __shared__ float A[16][256];
    const int tid = threadIdx.x;
    const int m0 = blockIdx.x * 16;
    for (int i = tid; i < 16 * EE; i += 256) {
        const int r = i >> 7, cc = i & (EE - 1);
        const int m = m0 + r;
        const int t = m >> 5, b = m & (BB - 1);
        const int id = idx[b * SS + t];
        A[r][cc] = xin[(size_t)id * EE + cc];
    }
    __syncthreads();
    const float4 b4 = ((const float4*)bias)[tid];
    float4 acc[16];
#pragma unroll
    for (int i = 0; i < 16; i++) acc[i] = b4;
    for (int r = 0; r < EE; r++) {
        const float4 w = ((const float4*)(Wk + (size_t)r * 1024))[tid];
#pragma unroll
        for (int i = 0; i < 16; i++) {
            const float a = A[i][r];
            acc[i].x += a * w.x; acc[i].y += a * w.y;
            acc[i].z += a * w.z; acc[i].w += a * w.w;
        }
    }
#pragma unroll
    for (int i = 0; i < 16; i++) {
        ushort_t o4[4] = { f2bf(acc[i].x), f2bf(acc[i].y), f2bf(acc[i].z), f2bf(acc[i].w) };
        *(uint2*)&Zb[(size_t)(m0 + i) * 1024 + 4 * tid] = *(uint2*)o4;
    }
}

// ---------------- h-part weights -> fp8 K=128 fragment layout (R12-validated) ----------
__global__ __launch_bounds__(256)
void wf8k128(const float* __restrict__ src, uchar_t* __restrict__ dst)
{
    const int nt = blockIdx.x;             // 0..63
    const int t = threadIdx.x;
    const int kk = t >> 7, h = (t >> 6) & 1, l = t & 63;
    const int q = l >> 4, n16 = l & 15;
    const int col = (nt >> 4) * 256 + (nt & 15) * 16 + n16;
    uchar_t v[16];
#pragma unroll
    for (int j = 0; j < 16; j++) {
        const int k = kk * 128 + q * 32 + h * 16 + j;
        v[j] = f2fp8(src[(size_t)k * 1024 + col]);
    }
    *(uint4*)&dst[(((size_t)(nt * 2 + kk) * 2 + h) * 64 + l) * 16] = *(uint4*)v;
}

// ---------------- fp32[256 x 1024] -> bf16 [1024][256] transpose (R6-validated) --------
__global__ __launch_bounds__(256)
void wtgen(const float* __restrict__ src, ushort_t* __restrict__ dst)
{
    __shared__ float tile[64][65];
    const int tid = threadIdx.x;
    const int n0 = blockIdx.x * 64, k0 = blockIdx.y * 64;
    for (int i = tid; i < 4096; i += 256) {
        const int kk = i >> 6, nn = i & 63;
        tile[kk][nn] = src[(size_t)(k0 + kk) * 1024 + n0 + nn];
    }
    __syncthreads();
    for (int i = tid; i < 4096; i += 256) {
        const int nn = i >> 6, kk = i & 63;
        dst[(size_t)(n0 + nn) * 256 + k0 + kk] = f2bf(tile[kk][nn]);
    }
}

// ---------------- out_W -> bf16 transpose + padded bias (R3-validated) ----------------
__global__ __launch_bounds__(256)
void wtrans_kernel(const float* __restrict__ W, ushort_t* __restrict__ Wt)
{
    __shared__ float tile[64][65];
    const int tid = threadIdx.x;
    const int n0 = blockIdx.x * 64, k0 = blockIdx.y * 64;
    for (int i = tid; i < 4096; i += 256) {
        const int kk = i >> 6, nn = i & 63;
        const int n = n0 + nn;
        tile[kk][nn] = (n < VV) ? W[(size_t)(k0 + kk) * VV + n] : 0.f;
    }
    __syncthreads();
    for (int i = tid; i < 4096; i += 256) {
        const int nn = i >> 6, kk = i & 63;
        Wt[(size_t)(n0 + nn) * 256 + k0 + kk] = f2bf(tile[kk][nn]);
    }
}

__global__ __launch_bounds__(256)
void obset_kernel(const float* __restrict__ ob, float* __restrict__ obp)
{
    const int v = blockIdx.x * 256 + threadIdx.x;
    if (v < VPAD) obp[v] = (v < VV) ? ob[v] : -INFINITY;
}

// ---------------- batch-parallel LSTM, K=128 scaled fp8 MFMA, 7V/6L/3S split ----------
// 1 block / batch element; 256 thr = 4 waves. Gate-aligned: wave w owns units
// [w*64,(w+1)*64); lane (q,n16) owns unit w*64+q*16+n16; tile (g,jj): nt=g*16+w*4+jj.
// Residency per wave (16 tiles), balanced across pipes (R12 PM: LDS port was the
// bottleneck at 9 LDS tiles = 1728 cy):
//   VGPR 7 {(g,0) g=0..3,(0,1),(1,1),(2,1)} = 112 regs
//   LDS  6 {(3,1),(g,2) g=0..3,(0,3)} = 24 KB/wave -> ~1128 cy/step
//   stream 3 {(1,3),(2,3),(3,3)} = 48 KB/CU/step warm L2 -> ~894 cy
//   MFMA 128/CU/step @ K=128 -> ~1106 cy
// h fp8 double-buffered LDS; ONE barrier/step; uniform early-exit (R9-validated).
__global__ __launch_bounds__(256, 1)
void lstm_mx(const uchar_t* __restrict__ Wsw, const ushort_t* __restrict__ zin,
             const int* __restrict__ lens, ushort_t* __restrict__ outp)
{
    __shared__ uchar_t Bl[98304];      // 24 tiles x 4 KB
    __shared__ uchar_t h8[2][256];
    const int tid = threadIdx.x;
    const int w = tid >> 6, lane = tid & 63;
    const int q = lane >> 4, n16 = lane & 15;
    const int b = blockIdx.x;
    const int len = lens[b];
    const int unit = w * 64 + q * 16 + n16;

    // LDS staging: wave-local tile list (g,jj)
    const int gl[6] = {3, 0, 1, 2, 3, 0};
    const int jl[6] = {1, 2, 2, 2, 2, 3};
#pragma unroll
    for (int li = 0; li < 6; li++) {
        const int nt = gl[li] * 16 + w * 4 + jl[li];
#pragma unroll
        for (int fh = 0; fh < 4; fh++) {
            const size_t s = (((size_t)nt * 4 + fh) * 64 + lane) * 16;
            const size_t d = (((size_t)(w * 6 + li) * 4 + fh) * 64 + lane) * 16;
            *(uint4*)&Bl[d] = *(const uint4*)&Wsw[s];
        }
    }
    // VGPR tiles: 0:(0,0) 1:(1,0) 2:(2,0) 3:(3,0) 4:(0,1) 5:(1,1) 6:(2,1)
    i32x8 Bv[7][2];
    {
        const int gv_[7] = {0, 1, 2, 3, 0, 1, 2}, jv_[7] = {0, 0, 0, 0, 1, 1, 1};
#pragma unroll
        for (int i = 0; i < 7; i++) {
            const int nt = gv_[i] * 16 + w * 4 + jv_[i];
#pragma unroll
            for (int kk = 0; kk < 2; kk++)
                Bv[i][kk] = ldfrag(&Wsw[(size_t)nt * 4096 + kk * 2048], lane);
        }
    }
    if (tid < 256) { h8[0][tid] = 0; h8[1][tid] = 0; }
    float c = 0.f;
    __syncthreads();

    const uchar_t* Lb0 = &Bl[(size_t)(w * 6) * 4096];   // wave's LDS region

    for (int t = 0; t < SS; t++) {
        if (t >= len) {                // uniform: zero remaining rows, done
            uint4 zz; zz.x = zz.y = zz.z = zz.w = 0u;
            const int nseg = (SS - t) * 32;
            for (int i = tid; i < nseg; i += 256) {
                const int tt = t + (i >> 5), seg = i & 31;
                *(uint4*)&outp[((size_t)tt * 32 + b) * 256 + seg * 8] = zz;
            }
            break;
        }
        const size_t row = (size_t)t * 32 + b;
        // streamed tiles (1,3),(2,3),(3,3) — issue first, consume last
        i32x8 St[3][2];
#pragma unroll
        for (int s = 0; s < 3; s++) {
            const int nt = (1 + s) * 16 + w * 4 + 3;
#pragma unroll
            for (int kk = 0; kk < 2; kk++)
                St[s][kk] = ldfrag(&Wsw[(size_t)nt * 4096 + kk * 2048], lane);
        }
        ushort_t z4[4];
#pragma unroll
        for (int g = 0; g < 4; g++) z4[g] = zin[row * 1024 + g * 256 + unit];

        const int rd = t & 1, wr = rd ^ 1;
        i32x8 Af0, Af1;                // A: rows identical (quad-broadcast from h8)
        ((uint4*)&Af0)[0] = *(const uint4*)&h8[rd][q * 32];
        ((uint4*)&Af0)[1] = *(const uint4*)&h8[rd][q * 32 + 16];
        ((uint4*)&Af1)[0] = *(const uint4*)&h8[rd][128 + q * 32];
        ((uint4*)&Af1)[1] = *(const uint4*)&h8[rd][128 + q * 32 + 16];

        float gvv[4];
        // ---- g = 0: V(0,0), V(0,1), L li1, L li5
        {
            f32x4 C0 = (f32x4){0,0,0,0}, C1 = C0, C2 = C0, C3 = C0;
            C0 = MFMAS(Af0, Bv[0][0], C0); C0 = MFMAS(Af1, Bv[0][1], C0);
            C1 = MFMAS(Af0, Bv[4][0], C1); C1 = MFMAS(Af1, Bv[4][1], C1);
            const uchar_t* p2 = Lb0 + 1 * 4096;
            C2 = MFMAS(Af0, ldfrag(p2, lane), C2); C2 = MFMAS(Af1, ldfrag(p2 + 2048, lane), C2);
            const uchar_t* p3 = Lb0 + 5 * 4096;
            C3 = MFMAS(Af0, ldfrag(p3, lane), C3); C3 = MFMAS(Af1, ldfrag(p3 + 2048, lane), C3);
            const float v01 = (q & 1) ? C1[0] : C0[0];
            const float v23 = (q & 1) ? C3[0] : C2[0];
            gvv[0] = (q & 2) ? v23 : v01;
        }
        // ---- g = 1: V(1,0), V(1,1), L li2, S0
        {
            f32x4 C0 = (f32x4){0,0,0,0}, C1 = C0, C2 = C0, C3 = C0;
            C0 = MFMAS(Af0, Bv[1][0], C0); C0 = MFMAS(Af1, Bv[1][1], C0);
            C1 = MFMAS(Af0, Bv[5][0], C1); C1 = MFMAS(Af1, Bv[5][1], C1);
            const uchar_t* p2 = Lb0 + 2 * 4096;
            C2 = MFMAS(Af0, ldfrag(p2, lane), C2); C2 = MFMAS(Af1, ldfrag(p2 + 2048, lane), C2);
            C3 = MFMAS(Af0, St[0][0], C3); C3 = MFMAS(Af1, St[0][1], C3);
            const float v01 = (q & 1) ? C1[0] : C0[0];
            const float v23 = (q & 1) ? C3[0] : C2[0];
            gvv[1] = (q & 2) ? v23 : v01;
        }
        // ---- g = 2: V(2,0), V(2,1), L li3, S1
        {
            f32x4 C0 = (f32x4){0,0,0,0}, C1 = C0, C2 = C0, C3 = C0;
            C0 = MFMAS(Af0, Bv[2][0], C0); C0 = MFMAS(Af1, Bv[2][1], C0);
            C1 = MFMAS(Af0, Bv[6][0], C1); C1 = MFMAS(Af1, Bv[6][1], C1);
            const uchar_t* p2 = Lb0 + 3 * 4096;
            C2 = MFMAS(Af0, ldfrag(p2, lane), C2); C2 = MFMAS(Af1, ldfrag(p2 + 2048, lane), C2);
            C3 = MFMAS(Af0, St[1][0], C3); C3 = MFMAS(Af1, St[1][1], C3);
            const float v01 = (q & 1) ? C1[0] : C0[0];
            const float v23 = (q & 1) ? C3[0] : C2[0];
            gvv[2] = (q & 2) ? v23 : v01;
        }
        // ---- g = 3: V(3,0), L li0, L li4, S2
        {
            f32x4 C0 = (f32x4){0,0,0,0}, C1 = C0, C2 = C0, C3 = C0;
            C0 = MFMAS(Af0, Bv[3][0], C0); C0 = MFMAS(Af1, Bv[3][1], C0);
            const uchar_t* p1 = Lb0 + 0 * 4096;
            C1 = MFMAS(Af0, ldfrag(p1, lane), C1); C1 = MFMAS(Af1, ldfrag(p1 + 2048, lane), C1);
            const uchar_t* p2 = Lb0 + 4 * 4096;
            C2 = MFMAS(Af0, ldfrag(p2, lane), C2); C2 = MFMAS(Af1, ldfrag(p2 + 2048, lane), C2);
            C3 = MFMAS(Af0, St[2][0], C3); C3 = MFMAS(Af1, St[2][1], C3);
            const float v01 = (q & 1) ? C1[0] : C0[0];
            const float v23 = (q & 1) ? C3[0] : C2[0];
            gvv[3] = (q & 2) ? v23 : v01;
        }
        {
            const float zi = bf2f(z4[0]) + gvv[0];
            const float zg = bf2f(z4[1]) + gvv[1];
            const float zf = bf2f(z4[2]) + gvv[2];
            const float zo = bf2f(z4[3]) + gvv[3];
            const float cn = sigf(zf + 1.0f) * c + sigf(zi) * tanhf_(zg);
            const float hn = sigf(zo) * tanhf_(cn);
            c = cn;
            h8[wr][unit] = f2fp8(hn);
            outp[row * 256 + unit] = f2bf(hn);
        }
        __syncthreads();               // h8[wr] complete + visible for next step
    }
}

// ---------------- layer-2 x-part GEMM + b1, plain bf16 out (R9-validated) ----------------
__global__ __launch_bounds__(512, 2)
void xgemm2p(const ushort_t* __restrict__ out1, const ushort_t* __restrict__ W2x,
             const float* __restrict__ b1v, ushort_t* __restrict__ Xp)
{
    const int tid = threadIdx.x;
    const int w = tid >> 6, lane = tid & 63;
    const int q = lane >> 4, n16 = lane & 15;
    const int m0 = blockIdx.x * 128;           // 4 timesteps x 32 batch
#pragma unroll 1
    for (int i = 0; i < 8; i++) {
        const int n = (w * 8 + i) * 16 + n16;
        bf16x8 Bfr[8];
#pragma unroll
        for (int kb = 0; kb < 8; kb++)
            Bfr[kb] = *(const bf16x8*)&W2x[(size_t)n * 256 + kb * 32 + q * 8];
        const float bval = b1v[n];
        f32x4 Cc[8];
#pragma unroll
        for (int mt = 0; mt < 8; mt++) {
            Cc[mt] = (f32x4){0.f, 0.f, 0.f, 0.f};
            bf16x8 Af[8];
#pragma unroll
            for (int kb = 0; kb < 8; kb++)
                Af[kb] = *(const bf16x8*)&out1[(size_t)(m0 + mt * 16 + n16) * 256 + kb * 32 + q * 8];
#pragma unroll
            for (int kb = 0; kb < 8; kb++)
                Cc[mt] = MFMA(Af[kb], Bfr[kb], Cc[mt]);
        }
#pragma unroll
        for (int mt = 0; mt < 8; mt++)
#pragma unroll
            for (int r = 0; r < 4; r++) {
                const int rrow = m0 + mt * 16 + q * 4 + r;
                Xp[(size_t)rrow * 1024 + n] = f2bf(Cc[mt][r] + bval);
            }
    }
}

// ---------------- MFMA bf16 fused projection + CE (R3-validated) ----------------
__global__ __launch_bounds__(256, 1)
void ce_kernel(const ushort_t* __restrict__ h2bf, const ushort_t* __restrict__ Wt,
               const float* __restrict__ obp, const int* __restrict__ y,
               const int* __restrict__ lens, float* __restrict__ out)
{
    __shared__ ushort_t h2t[64 * 264];
    __shared__ float lsw[4][64];
    __shared__ float tgt64[64];
    const int tid = threadIdx.x;
    const int w = tid >> 6, lane = tid & 63;
    const int q = lane >> 4, n16 = lane & 15;
    const int m0 = blockIdx.x * 64;

    for (int i = tid; i < 64 * 32; i += 256) {
        const int r = i >> 5, s = i & 31;
        *(uint4*)&h2t[r * 264 + s * 8] = *(const uint4*)(h2bf + (size_t)(m0 + r) * 256 + s * 8);
    }
    if (tid < 64) tgt64[tid] = 0.f;
    __syncthreads();

    bf16x8 A[4][8];
#pragma unroll
    for (int mt = 0; mt < 4; mt++) {
        const int row = mt * 16 + n16;
#pragma unroll
        for (int kb = 0; kb < 8; kb++)
            A[mt][kb] = *(const bf16x8*)&h2t[row * 264 + kb * 32 + q * 8];
    }
    int yv[16];
#pragma unroll
    for (int mt = 0; mt < 4; mt++)
#pragma unroll
        for (int r = 0; r < 4; r++) {
            const int m = m0 + mt * 16 + q * 4 + r;
            yv[mt * 4 + r] = y[(m & 31) * SS + (m >> 5)];
        }
    float lsum[16];
#pragma unroll
    for (int i = 0; i < 16; i++) lsum[i] = 0.f;

    const int cbase = w * 2512;
    for (int tile = 0; tile < 157; tile++) {
        const int n = cbase + tile * 16 + n16;
        const ushort_t* bp = Wt + (size_t)n * 256 + q * 8;
        bf16x8 B[8];
#pragma unroll
        for (int kb = 0; kb < 8; kb++) B[kb] = *(const bf16x8*)(bp + kb * 32);
        const float obv = obp[n];
        f32x4 C[4];
#pragma unroll
        for (int mt = 0; mt < 4; mt++) {
            C[mt] = (f32x4){0.f, 0.f, 0.f, 0.f};
#pragma unroll
            for (int kb = 0; kb < 8; kb++)
                C[mt] = MFMA(A[mt][kb], B[kb], C[mt]);
        }
#pragma unroll
        for (int mt = 0; mt < 4; mt++)
#pragma unroll
            for (int r = 0; r < 4; r++) {
                const float sc = C[mt][r] + obv;
                if (n == yv[mt * 4 + r]) tgt64[mt * 16 + q * 4 + r] = sc;
                lsum[mt * 4 + r] += __expf(sc - 16.0f);
            }
    }
#pragma unroll
    for (int i = 0; i < 16; i++) {
        float v = lsum[i];
        v += __shfl_xor(v, 1, 16); v += __shfl_xor(v, 2, 16);
        v += __shfl_xor(v, 4, 16); v += __shfl_xor(v, 8, 16);
        lsum[i] = v;
    }
    if (n16 == 0)
#pragma unroll
        for (int i = 0; i < 16; i++)
            lsw[w][(i >> 2) * 16 + q * 4 + (i & 3)] = lsum[i];
    __syncthreads();

    if (tid < 64) {
        const float l = lsw[0][tid] + lsw[1][tid] + lsw[2][tid] + lsw[3][tid];
        const float lse = 16.0f + __logf(l);
        const int m = m0 + tid;
        const int tt = m >> 5, bb = m & 31;
        const int yvv = y[bb * SS + tt];
        float local = (yvv != 0) ? (lse - tgt64[tid]) / (32.0f * (float)lens[bb]) : 0.f;
        for (int off = 1; off < 64; off <<= 1) local += __shfl_xor(local, off, 64);
        if (tid == 0) atomicAdd(out, local);
    }
}

extern "C" void kernel_launch(void* const* d_in, const int* in_sizes, int n_in,
                              void* d_out, int out_size, void* d_ws, size_t ws_size,
                              hipStream_t stream)
{
    const int*   input_x = (const int*)  d_in[0];
    const int*   input_y = (const int*)  d_in[1];
    const int*   lens    = (const int*)  d_in[2];
    const float* emb_W   = (const float*)d_in[3];
    const float* k0      = (const float*)d_in[4];
    const float* b0      = (const float*)d_in[5];
    const float* k1      = (const float*)d_in[6];
    const float* b1      = (const float*)d_in[7];
    const float* out_W   = (const float*)d_in[8];
    const float* out_b   = (const float*)d_in[9];
    float* out = (float*)d_out;

    char* p = (char*)d_ws;
    ushort_t* Zb   = (ushort_t*)p;  p += (size_t)NROWS * 1024 * 2;    // 33.55 MB
    ushort_t* Xp   = (ushort_t*)p;  p += (size_t)NROWS * 1024 * 2;    // 33.55 MB
    ushort_t* out1 = (ushort_t*)p;  p += (size_t)NROWS * 256 * 2;     // 8.39 MB
    ushort_t* h2bf = (ushort_t*)p;  p += (size_t)NROWS * 256 * 2;     // 8.39 MB
    uchar_t*  Wsw1 = (uchar_t*)p;   p += (size_t)1024 * 256;          // 256 KB
    uchar_t*  Wsw2 = (uchar_t*)p;   p += (size_t)1024 * 256;          // 256 KB
    ushort_t* W2x  = (ushort_t*)p;  p += (size_t)1024 * 256 * 2;      // 512 KB
    ushort_t* Wt   = (ushort_t*)p;  p += (size_t)VPAD * 256 * 2;      // 5.14 MB
    float*    obp  = (float*)p;     p += (size_t)VPAD * 4;

    hipMemsetAsync(d_out, 0, sizeof(float), stream);

    zgemm_b<<<NROWS / 16, 256, 0, stream>>>(k0, b0, emb_W, input_x, Zb);
    wf8k128<<<64, 256, 0, stream>>>(k0 + (size_t)EE * 1024, Wsw1);   // L1 h-part fp8 K128
    wf8k128<<<64, 256, 0, stream>>>(k1 + (size_t)HH * 1024, Wsw2);   // L2 h-part fp8 K128
    wtgen<<<dim3(16, 4), 256, 0, stream>>>(k1, W2x);                 // L2 x-part bf16
    wtrans_kernel<<<dim3(VPAD / 64, 4), 256, 0, stream>>>(out_W, Wt);
    obset_kernel<<<(VPAD + 255) / 256, 256, 0, stream>>>(out_b, obp);

    lstm_mx<<<BB, 256, 0, stream>>>(Wsw1, Zb, lens, out1);
    xgemm2p<<<128, 512, 0, stream>>>(out1, W2x, b1, Xp);
    lstm_mx<<<BB, 256, 0, stream>>>(Wsw2, Xp, lens, h2bf);
    ce_kernel<<<NROWS / 64, 256, 0, stream>>>(h2bf, Wt, obp, input_y, lens, out);
}

// Round 14
// 1769.555 us; speedup vs baseline: 1.1336x; 1.1336x over previous
//
#include <hip/hip_runtime.h>
#include <hip/hip_fp8.h>
#include <cmath>

#define SS 512
#define BB 32
#define EE 128
#define HH 256
#define VV 10000
#define NROWS (SS*BB)   // 16384
#define VPAD 10048
#define NT8 (VPAD/16)   // 628 fp8 B-tiles

typedef unsigned short ushort_t;
typedef unsigned char uchar_t;
typedef __attribute__((ext_vector_type(8))) short bf16x8;
typedef __attribute__((ext_vector_type(8))) int i32x8;
typedef __attribute__((ext_vector_type(4))) float f32x4;

#define MFMA(a,b,c)  __builtin_amdgcn_mfma_f32_16x16x32_bf16((a),(b),(c),0,0,0)
// fp8 x fp8, K=128, unit scales (E8M0 127 = 1.0) -> numerically plain fp8 matmul
#define MFMAS(a,b,c) __builtin_amdgcn_mfma_scale_f32_16x16x128_f8f6f4((a),(b),(c),0,0,0,0x7F7F7F7F,0,0x7F7F7F7F)

__device__ __forceinline__ ushort_t f2bf(float x) {
    unsigned u = __float_as_uint(x);
    u = (u + 0x7FFFu + ((u >> 16) & 1u)) >> 16;   // RNE
    return (ushort_t)u;
}
__device__ __forceinline__ float bf2f(ushort_t h) {
    return __uint_as_float(((unsigned)h) << 16);
}
__device__ __forceinline__ uchar_t f2fp8(float x) {
    __hip_fp8_e4m3 t(x);                           // OCP e4m3
    return (uchar_t)t.__x;
}
__device__ __forceinline__ float sigf(float x) { return 1.0f / (1.0f + __expf(-x)); }
__device__ __forceinline__ float tanhf_(float x) { return 1.0f - 2.0f / (__expf(2.0f * x) + 1.0f); }

// assemble a 32-B fp8 fragment from two 16-B halves 1024 B apart (LDS or global)
__device__ __forceinline__ i32x8 ldfrag(const uchar_t* base, int lane) {
    i32x8 r;
    ((uint4*)&r)[0] = *(const uint4*)(base + lane * 16);
    ((uint4*)&r)[1] = *(const uint4*)(base + 1024 + lane * 16);
    return r;
}

// ---------------- zgemm: layer-1 x-part (b0 folded), plain bf16 [row][1024] (R9-validated) ----
__global__ __launch_bounds__(256)
void zgemm_b(const float* __restrict__ Wk, const float* __restrict__ bias,
             const float* __restrict__ xin, const int* __restrict__ idx,
             ushort_t* __restrict__ Zb)
{
    __shared__ float A[16][256];
    const int tid = threadIdx.x;
    const int m0 = blockIdx.x * 16;
    for (int i = tid; i < 16 * EE; i += 256) {
        const int r = i >> 7, cc = i & (EE - 1);
        const int m = m0 + r;
        const int t = m >> 5, b = m & (BB - 1);
        const int id = idx[b * SS + t];
        A[r][cc] = xin[(size_t)id * EE + cc];
    }
    __syncthreads();
    const float4 b4 = ((const float4*)bias)[tid];
    float4 acc[16];
#pragma unroll
    for (int i = 0; i < 16; i++) acc[i] = b4;
    for (int r = 0; r < EE; r++) {
        const float4 w = ((const float4*)(Wk + (size_t)r * 1024))[tid];
#pragma unroll
        for (int i = 0; i < 16; i++) {
            const float a = A[i][r];
            acc[i].x += a * w.x; acc[i].y += a * w.y;
            acc[i].z += a * w.z; acc[i].w += a * w.w;
        }
    }
#pragma unroll
    for (int i = 0; i < 16; i++) {
        ushort_t o4[4] = { f2bf(acc[i].x), f2bf(acc[i].y), f2bf(acc[i].z), f2bf(acc[i].w) };
        *(uint2*)&Zb[(size_t)(m0 + i) * 1024 + 4 * tid] = *(uint2*)o4;
    }
}

// ---------------- h-part weights -> fp8 K=128 fragment layout (R12-validated) ----------
__global__ __launch_bounds__(256)
void wf8k128(const float* __restrict__ src, uchar_t* __restrict__ dst)
{
    const int nt = blockIdx.x;             // 0..63
    const int t = threadIdx.x;
    const int kk = t >> 7, h = (t >> 6) & 1, l = t & 63;
    const int q = l >> 4, n16 = l & 15;
    const int col = (nt >> 4) * 256 + (nt & 15) * 16 + n16;
    uchar_t v[16];
#pragma unroll
    for (int j = 0; j < 16; j++) {
        const int k = kk * 128 + q * 32 + h * 16 + j;
        v[j] = f2fp8(src[(size_t)k * 1024 + col]);
    }
    *(uint4*)&dst[(((size_t)(nt * 2 + kk) * 2 + h) * 64 + l) * 16] = *(uint4*)v;
}

// ---------------- out_W -> fp8 K=128 fragment layout, V padded to 10048 ----------------
// Same frag convention as wf8k128, but source is out_W [256 k][10000 n], pad n>=VV with 0.
__global__ __launch_bounds__(256)
void wtf8(const float* __restrict__ W, uchar_t* __restrict__ dst)
{
    const int nt = blockIdx.x;             // 0..627
    const int t = threadIdx.x;
    const int kk = t >> 7, h = (t >> 6) & 1, l = t & 63;
    const int q = l >> 4, n16 = l & 15;
    const int col = nt * 16 + n16;
    uchar_t v[16];
#pragma unroll
    for (int j = 0; j < 16; j++) {
        const int k = kk * 128 + q * 32 + h * 16 + j;
        v[j] = (col < VV) ? f2fp8(W[(size_t)k * VV + col]) : (uchar_t)0;
    }
    *(uint4*)&dst[(((size_t)(nt * 2 + kk) * 2 + h) * 64 + l) * 16] = *(uint4*)v;
}

// ---------------- fp32[256 x 1024] -> bf16 [1024][256] transpose (R6-validated) --------
__global__ __launch_bounds__(256)
void wtgen(const float* __restrict__ src, ushort_t* __restrict__ dst)
{
    __shared__ float tile[64][65];
    const int tid = threadIdx.x;
    const int n0 = blockIdx.x * 64, k0 = blockIdx.y * 64;
    for (int i = tid; i < 4096; i += 256) {
        const int kk = i >> 6, nn = i & 63;
        tile[kk][nn] = src[(size_t)(k0 + kk) * 1024 + n0 + nn];
    }
    __syncthreads();
    for (int i = tid; i < 4096; i += 256) {
        const int nn = i >> 6, kk = i & 63;
        dst[(size_t)(n0 + nn) * 256 + k0 + kk] = f2bf(tile[kk][nn]);
    }
}

__global__ __launch_bounds__(256)
void obset_kernel(const float* __restrict__ ob, float* __restrict__ obp)
{
    const int v = blockIdx.x * 256 + threadIdx.x;
    if (v < VPAD) obp[v] = (v < VV) ? ob[v] : -INFINITY;
}

// ---------------- batch-parallel LSTM, K=128 scaled fp8 MFMA (R12 config, 5V/9L/2S) ----
// 1 block / batch element; 256 thr = 4 waves. Gate-aligned: wave w owns units
// [w*64,(w+1)*64); lane (q,n16) owns unit w*64+q*16+n16; tile (g,jj): nt=g*16+w*4+jj.
// Residency per wave: VGPR {(g,0) g=0..3,(0,1)}; LDS 9 {(1,1),(2,1),(3,1),(g,2),(0,3),(1,3)};
// streamed {(2,3),(3,3)}. h fp8 double-buffered LDS; ONE barrier/step; uniform early-exit.
// Optionally also emits h fp8 (row-major [row][256]) for the fp8 CE (hf8 != nullptr).
__global__ __launch_bounds__(256, 1)
void lstm_mx(const uchar_t* __restrict__ Wsw, const ushort_t* __restrict__ zin,
             const int* __restrict__ lens, ushort_t* __restrict__ outp,
             uchar_t* __restrict__ hf8)
{
    __shared__ uchar_t Bl[147456];     // 36 tiles x 4 KB
    __shared__ uchar_t h8[2][256];
    const int tid = threadIdx.x;
    const int w = tid >> 6, lane = tid & 63;
    const int q = lane >> 4, n16 = lane & 15;
    const int b = blockIdx.x;
    const int len = lens[b];
    const int unit = w * 64 + q * 16 + n16;

    // LDS staging: wave-local tile list (g,jj)
    const int gl[9] = {1, 2, 3, 0, 1, 2, 3, 0, 1};
    const int jl[9] = {1, 1, 1, 2, 2, 2, 2, 3, 3};
#pragma unroll
    for (int li = 0; li < 9; li++) {
        const int nt = gl[li] * 16 + w * 4 + jl[li];
#pragma unroll
        for (int fh = 0; fh < 4; fh++) {
            const size_t s = (((size_t)nt * 4 + fh) * 64 + lane) * 16;
            const size_t d = (((size_t)(w * 9 + li) * 4 + fh) * 64 + lane) * 16;
            *(uint4*)&Bl[d] = *(const uint4*)&Wsw[s];
        }
    }
    // VGPR tiles
    i32x8 Bv[5][2];
    {
        const int gv_[5] = {0, 1, 2, 3, 0}, jv_[5] = {0, 0, 0, 0, 1};
#pragma unroll
        for (int i = 0; i < 5; i++) {
            const int nt = gv_[i] * 16 + w * 4 + jv_[i];
#pragma unroll
            for (int kk = 0; kk < 2; kk++)
                Bv[i][kk] = ldfrag(&Wsw[(size_t)nt * 4096 + kk * 2048], lane);
        }
    }
    if (tid < 256) { h8[0][tid] = 0; h8[1][tid] = 0; }
    float c = 0.f;
    __syncthreads();

    const uchar_t* Lb0 = &Bl[(size_t)(w * 9) * 4096];   // wave's LDS region

    for (int t = 0; t < SS; t++) {
        if (t >= len) {                // uniform: zero remaining rows, done
            uint4 zz; zz.x = zz.y = zz.z = zz.w = 0u;
            const int nseg = (SS - t) * 32;
            for (int i = tid; i < nseg; i += 256) {
                const int tt = t + (i >> 5), seg = i & 31;
                *(uint4*)&outp[((size_t)tt * 32 + b) * 256 + seg * 8] = zz;
            }
            if (hf8) {
                const int nseg8 = (SS - t) * 16;
                for (int i = tid; i < nseg8; i += 256) {
                    const int tt = t + (i >> 4), seg = i & 15;
                    *(uint4*)&hf8[((size_t)tt * 32 + b) * 256 + seg * 16] = zz;
                }
            }
            break;
        }
        const size_t row = (size_t)t * 32 + b;
        // streamed tiles (2,3),(3,3) — issue early, consume last
        i32x8 St[2][2];
#pragma unroll
        for (int s = 0; s < 2; s++) {
            const int nt = (2 + s) * 16 + w * 4 + 3;
#pragma unroll
            for (int kk = 0; kk < 2; kk++)
                St[s][kk] = ldfrag(&Wsw[(size_t)nt * 4096 + kk * 2048], lane);
        }
        ushort_t z4[4];
#pragma unroll
        for (int g = 0; g < 4; g++) z4[g] = zin[row * 1024 + g * 256 + unit];

        const int rd = t & 1, wr = rd ^ 1;
        i32x8 Af0, Af1;                // A: rows identical (quad-broadcast from h8)
        ((uint4*)&Af0)[0] = *(const uint4*)&h8[rd][q * 32];
        ((uint4*)&Af0)[1] = *(const uint4*)&h8[rd][q * 32 + 16];
        ((uint4*)&Af1)[0] = *(const uint4*)&h8[rd][128 + q * 32];
        ((uint4*)&Af1)[1] = *(const uint4*)&h8[rd][128 + q * 32 + 16];

        float gvv[4];
#pragma unroll
        for (int g = 0; g < 4; g++) {
            f32x4 C0 = (f32x4){0.f,0.f,0.f,0.f}, C1 = (f32x4){0.f,0.f,0.f,0.f};
            f32x4 C2 = (f32x4){0.f,0.f,0.f,0.f}, C3 = (f32x4){0.f,0.f,0.f,0.f};
            // jj=0: VGPR
            C0 = MFMAS(Af0, Bv[g][0], C0); C0 = MFMAS(Af1, Bv[g][1], C0);
            // jj=1: g==0 -> VGPR idx 4; else LDS li = g-1
            if (g == 0) {
                C1 = MFMAS(Af0, Bv[4][0], C1); C1 = MFMAS(Af1, Bv[4][1], C1);
            } else {
                const uchar_t* p = Lb0 + (size_t)(g - 1) * 4096;
                C1 = MFMAS(Af0, ldfrag(p, lane), C1);
                C1 = MFMAS(Af1, ldfrag(p + 2048, lane), C1);
            }
            // jj=2: LDS li = 3+g
            {
                const uchar_t* p = Lb0 + (size_t)(3 + g) * 4096;
                C2 = MFMAS(Af0, ldfrag(p, lane), C2);
                C2 = MFMAS(Af1, ldfrag(p + 2048, lane), C2);
            }
            // jj=3: g<2 -> LDS li = 7+g ; g>=2 -> streamed
            if (g < 2) {
                const uchar_t* p = Lb0 + (size_t)(7 + g) * 4096;
                C3 = MFMAS(Af0, ldfrag(p, lane), C3);
                C3 = MFMAS(Af1, ldfrag(p + 2048, lane), C3);
            } else {
                C3 = MFMAS(Af0, St[g - 2][0], C3);
                C3 = MFMAS(Af1, St[g - 2][1], C3);
            }
            const float v01 = (q & 1) ? C1[0] : C0[0];
            const float v23 = (q & 1) ? C3[0] : C2[0];
            gvv[g] = (q & 2) ? v23 : v01;
        }
        {
            const float zi = bf2f(z4[0]) + gvv[0];
            const float zg = bf2f(z4[1]) + gvv[1];
            const float zf = bf2f(z4[2]) + gvv[2];
            const float zo = bf2f(z4[3]) + gvv[3];
            const float cn = sigf(zf + 1.0f) * c + sigf(zi) * tanhf_(zg);
            const float hn = sigf(zo) * tanhf_(cn);
            c = cn;
            const uchar_t h8v = f2fp8(hn);
            h8[wr][unit] = h8v;
            outp[row * 256 + unit] = f2bf(hn);
            if (hf8) hf8[row * 256 + unit] = h8v;
        }
        __syncthreads();               // h8[wr] complete + visible for next step
    }
}

// ---------------- layer-2 x-part GEMM + b1, plain bf16 out (R9-validated) ----------------
__global__ __launch_bounds__(512, 2)
void xgemm2p(const ushort_t* __restrict__ out1, const ushort_t* __restrict__ W2x,
             const float* __restrict__ b1v, ushort_t* __restrict__ Xp)
{
    const int tid = threadIdx.x;
    const int w = tid >> 6, lane = tid & 63;
    const int q = lane >> 4, n16 = lane & 15;
    const int m0 = blockIdx.x * 128;           // 4 timesteps x 32 batch
#pragma unroll 1
    for (int i = 0; i < 8; i++) {
        const int n = (w * 8 + i) * 16 + n16;
        bf16x8 Bfr[8];
#pragma unroll
        for (int kb = 0; kb < 8; kb++)
            Bfr[kb] = *(const bf16x8*)&W2x[(size_t)n * 256 + kb * 32 + q * 8];
        const float bval = b1v[n];
        f32x4 Cc[8];
#pragma unroll
        for (int mt = 0; mt < 8; mt++) {
            Cc[mt] = (f32x4){0.f, 0.f, 0.f, 0.f};
            bf16x8 Af[8];
#pragma unroll
            for (int kb = 0; kb < 8; kb++)
                Af[kb] = *(const bf16x8*)&out1[(size_t)(m0 + mt * 16 + n16) * 256 + kb * 32 + q * 8];
#pragma unroll
            for (int kb = 0; kb < 8; kb++)
                Cc[mt] = MFMA(Af[kb], Bfr[kb], Cc[mt]);
        }
#pragma unroll
        for (int mt = 0; mt < 8; mt++)
#pragma unroll
            for (int r = 0; r < 4; r++) {
                const int rrow = m0 + mt * 16 + q * 4 + r;
                Xp[(size_t)rrow * 1024 + n] = f2bf(Cc[mt][r] + bval);
            }
    }
}

// ---------------- fp8 K=128 fused projection + CE ----------------
// Block: 64 rows; 256 thr = 4 waves, wave w sweeps tiles nt = w*157..+156.
// A-frags straight from global hf8 (row-major): lane k = kk*128 + q*32 + j.
// B from Wt8 (2.57 MB — fits per-XCD L2). Fixed-max (16) softmax as in R3-R13.
__global__ __launch_bounds__(256, 1)
void ce_kernel(const uchar_t* __restrict__ hf8, const uchar_t* __restrict__ Wt8,
               const float* __restrict__ obp, const int* __restrict__ y,
               const int* __restrict__ lens, float* __restrict__ out)
{
    __shared__ float lsw[4][64];
    __shared__ float tgt64[64];
    const int tid = threadIdx.x;
    const int w = tid >> 6, lane = tid & 63;
    const int q = lane >> 4, n16 = lane & 15;
    const int m0 = blockIdx.x * 64;

    if (tid < 64) tgt64[tid] = 0.f;

    i32x8 A8[4][2];
#pragma unroll
    for (int mt = 0; mt < 4; mt++) {
        const size_t rbase = (size_t)(m0 + mt * 16 + n16) * 256;
#pragma unroll
        for (int kk = 0; kk < 2; kk++) {
            ((uint4*)&A8[mt][kk])[0] = *(const uint4*)&hf8[rbase + kk * 128 + q * 32];
            ((uint4*)&A8[mt][kk])[1] = *(const uint4*)&hf8[rbase + kk * 128 + q * 32 + 16];
        }
    }
    int yv[16];
#pragma unroll
    for (int mt = 0; mt < 4; mt++)
#pragma unroll
        for (int r = 0; r < 4; r++) {
            const int m = m0 + mt * 16 + q * 4 + r;
            yv[mt * 4 + r] = y[(m & 31) * SS + (m >> 5)];
        }
    float lsum[16];
#pragma unroll
    for (int i = 0; i < 16; i++) lsum[i] = 0.f;
    __syncthreads();                   // tgt64 init visible

    for (int tile = 0; tile < 157; tile++) {
        const int nt = w * 157 + tile;
        const int n = nt * 16 + n16;
        const i32x8 B0 = ldfrag(&Wt8[(size_t)(nt * 2 + 0) * 2048], lane);
        const i32x8 B1 = ldfrag(&Wt8[(size_t)(nt * 2 + 1) * 2048], lane);
        const float obv = obp[n];
        f32x4 C[4];
#pragma unroll
        for (int mt = 0; mt < 4; mt++) {
            C[mt] = (f32x4){0.f, 0.f, 0.f, 0.f};
            C[mt] = MFMAS(A8[mt][0], B0, C[mt]);
            C[mt] = MFMAS(A8[mt][1], B1, C[mt]);
        }
#pragma unroll
        for (int mt = 0; mt < 4; mt++)
#pragma unroll
            for (int r = 0; r < 4; r++) {
                const float sc = C[mt][r] + obv;     // -inf on padded cols
                if (n == yv[mt * 4 + r]) tgt64[mt * 16 + q * 4 + r] = sc;
                lsum[mt * 4 + r] += __expf(sc - 16.0f);
            }
    }
#pragma unroll
    for (int i = 0; i < 16; i++) {
        float v = lsum[i];
        v += __shfl_xor(v, 1, 16); v += __shfl_xor(v, 2, 16);
        v += __shfl_xor(v, 4, 16); v += __shfl_xor(v, 8, 16);
        lsum[i] = v;
    }
    if (n16 == 0)
#pragma unroll
        for (int i = 0; i < 16; i++)
            lsw[w][(i >> 2) * 16 + q * 4 + (i & 3)] = lsum[i];
    __syncthreads();

    if (tid < 64) {
        const float l = lsw[0][tid] + lsw[1][tid] + lsw[2][tid] + lsw[3][tid];
        const float lse = 16.0f + __logf(l);
        const int m = m0 + tid;
        const int tt = m >> 5, bb = m & 31;
        const int yvv = y[bb * SS + tt];
        float local = (yvv != 0) ? (lse - tgt64[tid]) / (32.0f * (float)lens[bb]) : 0.f;
        for (int off = 1; off < 64; off <<= 1) local += __shfl_xor(local, off, 64);
        if (tid == 0) atomicAdd(out, local);
    }
}

extern "C" void kernel_launch(void* const* d_in, const int* in_sizes, int n_in,
                              void* d_out, int out_size, void* d_ws, size_t ws_size,
                              hipStream_t stream)
{
    const int*   input_x = (const int*)  d_in[0];
    const int*   input_y = (const int*)  d_in[1];
    const int*   lens    = (const int*)  d_in[2];
    const float* emb_W   = (const float*)d_in[3];
    const float* k0      = (const float*)d_in[4];
    const float* b0      = (const float*)d_in[5];
    const float* k1      = (const float*)d_in[6];
    const float* b1      = (const float*)d_in[7];
    const float* out_W   = (const float*)d_in[8];
    const float* out_b   = (const float*)d_in[9];
    float* out = (float*)d_out;

    char* p = (char*)d_ws;
    ushort_t* Zb   = (ushort_t*)p;  p += (size_t)NROWS * 1024 * 2;    // 33.55 MB
    ushort_t* Xp   = (ushort_t*)p;  p += (size_t)NROWS * 1024 * 2;    // 33.55 MB
    ushort_t* out1 = (ushort_t*)p;  p += (size_t)NROWS * 256 * 2;     // 8.39 MB
    ushort_t* h2bf = (ushort_t*)p;  p += (size_t)NROWS * 256 * 2;     // 8.39 MB
    uchar_t*  h2f8 = (uchar_t*)p;   p += (size_t)NROWS * 256;         // 4.19 MB
    uchar_t*  Wsw1 = (uchar_t*)p;   p += (size_t)1024 * 256;          // 256 KB
    uchar_t*  Wsw2 = (uchar_t*)p;   p += (size_t)1024 * 256;          // 256 KB
    ushort_t* W2x  = (ushort_t*)p;  p += (size_t)1024 * 256 * 2;      // 512 KB
    uchar_t*  Wt8  = (uchar_t*)p;   p += (size_t)NT8 * 4096;          // 2.57 MB
    float*    obp  = (float*)p;     p += (size_t)VPAD * 4;

    hipMemsetAsync(d_out, 0, sizeof(float), stream);

    zgemm_b<<<NROWS / 16, 256, 0, stream>>>(k0, b0, emb_W, input_x, Zb);
    wf8k128<<<64, 256, 0, stream>>>(k0 + (size_t)EE * 1024, Wsw1);   // L1 h-part fp8 K128
    wf8k128<<<64, 256, 0, stream>>>(k1 + (size_t)HH * 1024, Wsw2);   // L2 h-part fp8 K128
    wtgen<<<dim3(16, 4), 256, 0, stream>>>(k1, W2x);                 // L2 x-part bf16
    wtf8<<<NT8, 256, 0, stream>>>(out_W, Wt8);                       // out_W fp8 K128
    obset_kernel<<<(VPAD + 255) / 256, 256, 0, stream>>>(out_b, obp);

    lstm_mx<<<BB, 256, 0, stream>>>(Wsw1, Zb, lens, out1, nullptr);
    xgemm2p<<<128, 512, 0, stream>>>(out1, W2x, b1, Xp);
    lstm_mx<<<BB, 256, 0, stream>>>(Wsw2, Xp, lens, h2bf, h2f8);
    ce_kernel<<<NROWS / 64, 256, 0, stream>>>(h2f8, Wt8, obp, input_y, lens, out);
}

// Round 15
// 1705.252 us; speedup vs baseline: 1.1764x; 1.0377x over previous
//
#include <hip/hip_runtime.h>
#include <hip/hip_fp8.h>
#include <cmath>

#define SS 512
#define BB 32
#define EE 128
#define HH 256
#define VV 10000
#define NROWS (SS*BB)   // 16384
#define VPAD 10048
#define NT8 (VPAD/16)   // 628 fp8 B-tiles

typedef unsigned short ushort_t;
typedef unsigned char uchar_t;
typedef __attribute__((ext_vector_type(8))) short bf16x8;
typedef __attribute__((ext_vector_type(8))) int i32x8;
typedef __attribute__((ext_vector_type(4))) float f32x4;

#define MFMA(a,b,c)  __builtin_amdgcn_mfma_f32_16x16x32_bf16((a),(b),(c),0,0,0)
// fp8 x fp8, K=128, unit scales (E8M0 127 = 1.0) -> numerically plain fp8 matmul
#define MFMAS(a,b,c) __builtin_amdgcn_mfma_scale_f32_16x16x128_f8f6f4((a),(b),(c),0,0,0,0x7F7F7F7F,0,0x7F7F7F7F)

__device__ __forceinline__ ushort_t f2bf(float x) {
    unsigned u = __float_as_uint(x);
    u = (u + 0x7FFFu + ((u >> 16) & 1u)) >> 16;   // RNE
    return (ushort_t)u;
}
__device__ __forceinline__ float bf2f(ushort_t h) {
    return __uint_as_float(((unsigned)h) << 16);
}
__device__ __forceinline__ uchar_t f2fp8(float x) {
    __hip_fp8_e4m3 t(x);                           // OCP e4m3
    return (uchar_t)t.__x;
}
__device__ __forceinline__ float sigf(float x) { return 1.0f / (1.0f + __expf(-x)); }
__device__ __forceinline__ float tanhf_(float x) { return 1.0f - 2.0f / (__expf(2.0f * x) + 1.0f); }

// assemble a 32-B fp8 fragment from two 16-B halves 1024 B apart (LDS or global)
__device__ __forceinline__ i32x8 ldfrag(const uchar_t* base, int lane) {
    i32x8 r;
    ((uint4*)&r)[0] = *(const uint4*)(base + lane * 16);
    ((uint4*)&r)[1] = *(const uint4*)(base + 1024 + lane * 16);
    return r;
}

// ---------------- zgemm: layer-1 x-part (b0 folded), plain bf16 [row][1024] (R9-validated) ----
__global__ __launch_bounds__(256)
void zgemm_b(const float* __restrict__ Wk, const float* __restrict__ bias,
             const float* __restrict__ xin, const int* __restrict__ idx,
             ushort_t* __restrict__ Zb)
{
    __shared__ float A[16][256];
    const int tid = threadIdx.x;
    const int m0 = blockIdx.x * 16;
    for (int i = tid; i < 16 * EE; i += 256) {
        const int r = i >> 7, cc = i & (EE - 1);
        const int m = m0 + r;
        const int t = m >> 5, b = m & (BB - 1);
        const int id = idx[b * SS + t];
        A[r][cc] = xin[(size_t)id * EE + cc];
    }
    __syncthreads();
    const float4 b4 = ((const float4*)bias)[tid];
    float4 acc[16];
#pragma unroll
    for (int i = 0; i < 16; i++) acc[i] = b4;
    for (int r = 0; r < EE; r++) {
        const float4 w = ((const float4*)(Wk + (size_t)r * 1024))[tid];
#pragma unroll
        for (int i = 0; i < 16; i++) {
            const float a = A[i][r];
            acc[i].x += a * w.x; acc[i].y += a * w.y;
            acc[i].z += a * w.z; acc[i].w += a * w.w;
        }
    }
#pragma unroll
    for (int i = 0; i < 16; i++) {
        ushort_t o4[4] = { f2bf(acc[i].x), f2bf(acc[i].y), f2bf(acc[i].z), f2bf(acc[i].w) };
        *(uint2*)&Zb[(size_t)(m0 + i) * 1024 + 4 * tid] = *(uint2*)o4;
    }
}

// ---------------- h-part weights -> fp8 K=128 fragment layout (R12-validated) ----------
__global__ __launch_bounds__(256)
void wf8k128(const float* __restrict__ src, uchar_t* __restrict__ dst)
{
    const int nt = blockIdx.x;             // 0..63
    const int t = threadIdx.x;
    const int kk = t >> 7, h = (t >> 6) & 1, l = t & 63;
    const int q = l >> 4, n16 = l & 15;
    const int col = (nt >> 4) * 256 + (nt & 15) * 16 + n16;
    uchar_t v[16];
#pragma unroll
    for (int j = 0; j < 16; j++) {
        const int k = kk * 128 + q * 32 + h * 16 + j;
        v[j] = f2fp8(src[(size_t)k * 1024 + col]);
    }
    *(uint4*)&dst[(((size_t)(nt * 2 + kk) * 2 + h) * 64 + l) * 16] = *(uint4*)v;
}

// ---------------- out_W -> fp8 K=128 fragment layout, V padded (R14-validated) ---------
__global__ __launch_bounds__(256)
void wtf8(const float* __restrict__ W, uchar_t* __restrict__ dst)
{
    const int nt = blockIdx.x;             // 0..627
    const int t = threadIdx.x;
    const int kk = t >> 7, h = (t >> 6) & 1, l = t & 63;
    const int q = l >> 4, n16 = l & 15;
    const int col = nt * 16 + n16;
    uchar_t v[16];
#pragma unroll
    for (int j = 0; j < 16; j++) {
        const int k = kk * 128 + q * 32 + h * 16 + j;
        v[j] = (col < VV) ? f2fp8(W[(size_t)k * VV + col]) : (uchar_t)0;
    }
    *(uint4*)&dst[(((size_t)(nt * 2 + kk) * 2 + h) * 64 + l) * 16] = *(uint4*)v;
}

// ---------------- fp32[256 x 1024] -> bf16 [1024][256] transpose (R6-validated) --------
__global__ __launch_bounds__(256)
void wtgen(const float* __restrict__ src, ushort_t* __restrict__ dst)
{
    __shared__ float tile[64][65];
    const int tid = threadIdx.x;
    const int n0 = blockIdx.x * 64, k0 = blockIdx.y * 64;
    for (int i = tid; i < 4096; i += 256) {
        const int kk = i >> 6, nn = i & 63;
        tile[kk][nn] = src[(size_t)(k0 + kk) * 1024 + n0 + nn];
    }
    __syncthreads();
    for (int i = tid; i < 4096; i += 256) {
        const int nn = i >> 6, kk = i & 63;
        dst[(size_t)(n0 + nn) * 256 + k0 + kk] = f2bf(tile[kk][nn]);
    }
}

__global__ __launch_bounds__(256)
void obset_kernel(const float* __restrict__ ob, float* __restrict__ obp)
{
    const int v = blockIdx.x * 256 + threadIdx.x;
    if (v < VPAD) obp[v] = (v < VV) ? ob[v] : -INFINITY;
}

// ---------------- batch-parallel LSTM, K=128 fp8, 8 waves (2/SIMD) ----------------
// 1 block / batch element; 512 thr = 8 waves -> inter-wave MFMA/LDS overlap (m114).
// Wave w owns units [w*32,(w+1)*32); lane (q,n16) owns unit w*32+(q>>1)*16+n16
// (each unit owned by 2 lanes computing identical values — benign dup stores).
// Tile (g,j): nt = g*16 + w*2 + j. Residency per wave (8 tiles), sized to fit the
// ~128-VGPR allocator envelope (R7/R8/R11/R13 lesson):
//   VGPR 3 {(0,0),(1,0),(2,0)} = 48 regs
//   LDS  4 {(3,0),(0,1),(1,1),(2,1)} = 16 KB/wave (128 KB/CU, staged once)
//   stream 1 {(3,1)} = 4 KB/wave/step warm L2
// h fp8 double-buffered LDS; ONE barrier/step; uniform early-exit (R9-validated).
__global__ __launch_bounds__(512, 2)
void lstm_mx8(const uchar_t* __restrict__ Wsw, const ushort_t* __restrict__ zin,
              const int* __restrict__ lens, ushort_t* __restrict__ outp,
              uchar_t* __restrict__ hf8)
{
    __shared__ uchar_t Bl[131072];     // 8 waves x 4 tiles x 4 KB
    __shared__ uchar_t h8[2][256];
    const int tid = threadIdx.x;
    const int w = tid >> 6, lane = tid & 63;
    const int q = lane >> 4, n16 = lane & 15;
    const int b = blockIdx.x;
    const int len = lens[b];
    const int jown = q >> 1;
    const int unit = w * 32 + jown * 16 + n16;

    // LDS staging: wave-local tiles {(3,0),(0,1),(1,1),(2,1)}
    const int gl[4] = {3, 0, 1, 2};
    const int jl[4] = {0, 1, 1, 1};
#pragma unroll
    for (int li = 0; li < 4; li++) {
        const int nt = gl[li] * 16 + w * 2 + jl[li];
#pragma unroll
        for (int fh = 0; fh < 4; fh++) {
            const size_t s = (((size_t)nt * 4 + fh) * 64 + lane) * 16;
            const size_t d = (((size_t)(w * 4 + li) * 4 + fh) * 64 + lane) * 16;
            *(uint4*)&Bl[d] = *(const uint4*)&Wsw[s];
        }
    }
    // VGPR tiles {(0,0),(1,0),(2,0)}
    i32x8 Bv[3][2];
#pragma unroll
    for (int g = 0; g < 3; g++) {
        const int nt = g * 16 + w * 2;
#pragma unroll
        for (int kk = 0; kk < 2; kk++)
            Bv[g][kk] = ldfrag(&Wsw[(size_t)nt * 4096 + kk * 2048], lane);
    }
    if (tid < 256) { h8[0][tid] = 0; h8[1][tid] = 0; }
    float c = 0.f;
    __syncthreads();

    const uchar_t* Lb0 = &Bl[(size_t)(w * 4) * 4096];   // wave's LDS region

    for (int t = 0; t < SS; t++) {
        if (t >= len) {                // uniform: zero remaining rows, done
            uint4 zz; zz.x = zz.y = zz.z = zz.w = 0u;
            const int nseg = (SS - t) * 32;
            for (int i = tid; i < nseg; i += 512) {
                const int tt = t + (i >> 5), seg = i & 31;
                *(uint4*)&outp[((size_t)tt * 32 + b) * 256 + seg * 8] = zz;
            }
            if (hf8) {
                const int nseg8 = (SS - t) * 16;
                for (int i = tid; i < nseg8; i += 512) {
                    const int tt = t + (i >> 4), seg = i & 15;
                    *(uint4*)&hf8[((size_t)tt * 32 + b) * 256 + seg * 16] = zz;
                }
            }
            break;
        }
        const size_t row = (size_t)t * 32 + b;
        // streamed tile (3,1) — issue first, consume last
        i32x8 St[2];
        {
            const int nt = 3 * 16 + w * 2 + 1;
#pragma unroll
            for (int kk = 0; kk < 2; kk++)
                St[kk] = ldfrag(&Wsw[(size_t)nt * 4096 + kk * 2048], lane);
        }
        ushort_t z4[4];
#pragma unroll
        for (int g = 0; g < 4; g++) z4[g] = zin[row * 1024 + g * 256 + unit];

        const int rd = t & 1, wr = rd ^ 1;
        i32x8 Af0, Af1;                // A: rows identical (quad-broadcast from h8)
        ((uint4*)&Af0)[0] = *(const uint4*)&h8[rd][q * 32];
        ((uint4*)&Af0)[1] = *(const uint4*)&h8[rd][q * 32 + 16];
        ((uint4*)&Af1)[0] = *(const uint4*)&h8[rd][128 + q * 32];
        ((uint4*)&Af1)[1] = *(const uint4*)&h8[rd][128 + q * 32 + 16];

        float gvv[4];
#pragma unroll
        for (int g = 0; g < 4; g++) {
            f32x4 C0 = (f32x4){0.f,0.f,0.f,0.f}, C1 = (f32x4){0.f,0.f,0.f,0.f};
            if (g < 3) {               // j=0 from VGPR
                C0 = MFMAS(Af0, Bv[g][0], C0);
                C0 = MFMAS(Af1, Bv[g][1], C0);
            } else {                   // (3,0) from LDS li0
                C0 = MFMAS(Af0, ldfrag(Lb0, lane), C0);
                C0 = MFMAS(Af1, ldfrag(Lb0 + 2048, lane), C0);
            }
            if (g < 3) {               // (g,1) from LDS li = 1+g
                const uchar_t* p = Lb0 + (size_t)(1 + g) * 4096;
                C1 = MFMAS(Af0, ldfrag(p, lane), C1);
                C1 = MFMAS(Af1, ldfrag(p + 2048, lane), C1);
            } else {                   // (3,1) streamed
                C1 = MFMAS(Af0, St[0], C1);
                C1 = MFMAS(Af1, St[1], C1);
            }
            gvv[g] = jown ? C1[0] : C0[0];   // rows identical; col = n16 of owned tile
        }
        {
            const float zi = bf2f(z4[0]) + gvv[0];
            const float zg = bf2f(z4[1]) + gvv[1];
            const float zf = bf2f(z4[2]) + gvv[2];
            const float zo = bf2f(z4[3]) + gvv[3];
            const float cn = sigf(zf + 1.0f) * c + sigf(zi) * tanhf_(zg);
            const float hn = sigf(zo) * tanhf_(cn);
            c = cn;
            const uchar_t h8v = f2fp8(hn);
            h8[wr][unit] = h8v;                       // dup lanes write same value
            outp[row * 256 + unit] = f2bf(hn);
            if (hf8) hf8[row * 256 + unit] = h8v;
        }
        __syncthreads();               // h8[wr] complete + visible for next step
    }
}

// ---------------- layer-2 x-part GEMM + b1, plain bf16 out (R9-validated) ----------------
__global__ __launch_bounds__(512, 2)
void xgemm2p(const ushort_t* __restrict__ out1, const ushort_t* __restrict__ W2x,
             const float* __restrict__ b1v, ushort_t* __restrict__ Xp)
{
    const int tid = threadIdx.x;
    const int w = tid >> 6, lane = tid & 63;
    const int q = lane >> 4, n16 = lane & 15;
    const int m0 = blockIdx.x * 128;           // 4 timesteps x 32 batch
#pragma unroll 1
    for (int i = 0; i < 8; i++) {
        const int n = (w * 8 + i) * 16 + n16;
        bf16x8 Bfr[8];
#pragma unroll
        for (int kb = 0; kb < 8; kb++)
            Bfr[kb] = *(const bf16x8*)&W2x[(size_t)n * 256 + kb * 32 + q * 8];
        const float bval = b1v[n];
        f32x4 Cc[8];
#pragma unroll
        for (int mt = 0; mt < 8; mt++) {
            Cc[mt] = (f32x4){0.f, 0.f, 0.f, 0.f};
            bf16x8 Af[8];
#pragma unroll
            for (int kb = 0; kb < 8; kb++)
                Af[kb] = *(const bf16x8*)&out1[(size_t)(m0 + mt * 16 + n16) * 256 + kb * 32 + q * 8];
#pragma unroll
            for (int kb = 0; kb < 8; kb++)
                Cc[mt] = MFMA(Af[kb], Bfr[kb], Cc[mt]);
        }
#pragma unroll
        for (int mt = 0; mt < 8; mt++)
#pragma unroll
            for (int r = 0; r < 4; r++) {
                const int rrow = m0 + mt * 16 + q * 4 + r;
                Xp[(size_t)rrow * 1024 + n] = f2bf(Cc[mt][r] + bval);
            }
    }
}

// ---------------- fp8 K=128 fused projection + CE (R14-validated) ----------------
__global__ __launch_bounds__(256, 1)
void ce_kernel(const uchar_t* __restrict__ hf8, const uchar_t* __restrict__ Wt8,
               const float* __restrict__ obp, const int* __restrict__ y,
               const int* __restrict__ lens, float* __restrict__ out)
{
    __shared__ float lsw[4][64];
    __shared__ float tgt64[64];
    const int tid = threadIdx.x;
    const int w = tid >> 6, lane = tid & 63;
    const int q = lane >> 4, n16 = lane & 15;
    const int m0 = blockIdx.x * 64;

    if (tid < 64) tgt64[tid] = 0.f;

    i32x8 A8[4][2];
#pragma unroll
    for (int mt = 0; mt < 4; mt++) {
        const size_t rbase = (size_t)(m0 + mt * 16 + n16) * 256;
#pragma unroll
        for (int kk = 0; kk < 2; kk++) {
            ((uint4*)&A8[mt][kk])[0] = *(const uint4*)&hf8[rbase + kk * 128 + q * 32];
            ((uint4*)&A8[mt][kk])[1] = *(const uint4*)&hf8[rbase + kk * 128 + q * 32 + 16];
        }
    }
    int yv[16];
#pragma unroll
    for (int mt = 0; mt < 4; mt++)
#pragma unroll
        for (int r = 0; r < 4; r++) {
            const int m = m0 + mt * 16 + q * 4 + r;
            yv[mt * 4 + r] = y[(m & 31) * SS + (m >> 5)];
        }
    float lsum[16];
#pragma unroll
    for (int i = 0; i < 16; i++) lsum[i] = 0.f;
    __syncthreads();                   // tgt64 init visible

    for (int tile = 0; tile < 157; tile++) {
        const int nt = w * 157 + tile;
        const int n = nt * 16 + n16;
        const i32x8 B0 = ldfrag(&Wt8[(size_t)(nt * 2 + 0) * 2048], lane);
        const i32x8 B1 = ldfrag(&Wt8[(size_t)(nt * 2 + 1) * 2048], lane);
        const float obv = obp[n];
        f32x4 C[4];
#pragma unroll
        for (int mt = 0; mt < 4; mt++) {
            C[mt] = (f32x4){0.f, 0.f, 0.f, 0.f};
            C[mt] = MFMAS(A8[mt][0], B0, C[mt]);
            C[mt] = MFMAS(A8[mt][1], B1, C[mt]);
        }
#pragma unroll
        for (int mt = 0; mt < 4; mt++)
#pragma unroll
            for (int r = 0; r < 4; r++) {
                const float sc = C[mt][r] + obv;     // -inf on padded cols
                if (n == yv[mt * 4 + r]) tgt64[mt * 16 + q * 4 + r] = sc;
                lsum[mt * 4 + r] += __expf(sc - 16.0f);
            }
    }
#pragma unroll
    for (int i = 0; i < 16; i++) {
        float v = lsum[i];
        v += __shfl_xor(v, 1, 16); v += __shfl_xor(v, 2, 16);
        v += __shfl_xor(v, 4, 16); v += __shfl_xor(v, 8, 16);
        lsum[i] = v;
    }
    if (n16 == 0)
#pragma unroll
        for (int i = 0; i < 16; i++)
            lsw[w][(i >> 2) * 16 + q * 4 + (i & 3)] = lsum[i];
    __syncthreads();

    if (tid < 64) {
        const float l = lsw[0][tid] + lsw[1][tid] + lsw[2][tid] + lsw[3][tid];
        const float lse = 16.0f + __logf(l);
        const int m = m0 + tid;
        const int tt = m >> 5, bb = m & 31;
        const int yvv = y[bb * SS + tt];
        float local = (yvv != 0) ? (lse - tgt64[tid]) / (32.0f * (float)lens[bb]) : 0.f;
        for (int off = 1; off < 64; off <<= 1) local += __shfl_xor(local, off, 64);
        if (tid == 0) atomicAdd(out, local);
    }
}

extern "C" void kernel_launch(void* const* d_in, const int* in_sizes, int n_in,
                              void* d_out, int out_size, void* d_ws, size_t ws_size,
                              hipStream_t stream)
{
    const int*   input_x = (const int*)  d_in[0];
    const int*   input_y = (const int*)  d_in[1];
    const int*   lens    = (const int*)  d_in[2];
    const float* emb_W   = (const float*)d_in[3];
    const float* k0      = (const float*)d_in[4];
    const float* b0      = (const float*)d_in[5];
    const float* k1      = (const float*)d_in[6];
    const float* b1      = (const float*)d_in[7];
    const float* out_W   = (const float*)d_in[8];
    const float* out_b   = (const float*)d_in[9];
    float* out = (float*)d_out;

    char* p = (char*)d_ws;
    ushort_t* Zb   = (ushort_t*)p;  p += (size_t)NROWS * 1024 * 2;    // 33.55 MB
    ushort_t* Xp   = (ushort_t*)p;  p += (size_t)NROWS * 1024 * 2;    // 33.55 MB
    ushort_t* out1 = (ushort_t*)p;  p += (size_t)NROWS * 256 * 2;     // 8.39 MB
    ushort_t* h2bf = (ushort_t*)p;  p += (size_t)NROWS * 256 * 2;     // 8.39 MB
    uchar_t*  h2f8 = (uchar_t*)p;   p += (size_t)NROWS * 256;         // 4.19 MB
    uchar_t*  Wsw1 = (uchar_t*)p;   p += (size_t)1024 * 256;          // 256 KB
    uchar_t*  Wsw2 = (uchar_t*)p;   p += (size_t)1024 * 256;          // 256 KB
    ushort_t* W2x  = (ushort_t*)p;  p += (size_t)1024 * 256 * 2;      // 512 KB
    uchar_t*  Wt8  = (uchar_t*)p;   p += (size_t)NT8 * 4096;          // 2.57 MB
    float*    obp  = (float*)p;     p += (size_t)VPAD * 4;

    hipMemsetAsync(d_out, 0, sizeof(float), stream);

    zgemm_b<<<NROWS / 16, 256, 0, stream>>>(k0, b0, emb_W, input_x, Zb);
    wf8k128<<<64, 256, 0, stream>>>(k0 + (size_t)EE * 1024, Wsw1);   // L1 h-part fp8 K128
    wf8k128<<<64, 256, 0, stream>>>(k1 + (size_t)HH * 1024, Wsw2);   // L2 h-part fp8 K128
    wtgen<<<dim3(16, 4), 256, 0, stream>>>(k1, W2x);                 // L2 x-part bf16
    wtf8<<<NT8, 256, 0, stream>>>(out_W, Wt8);                       // out_W fp8 K128
    obset_kernel<<<(VPAD + 255) / 256, 256, 0, stream>>>(out_b, obp);

    lstm_mx8<<<BB, 512, 0, stream>>>(Wsw1, Zb, lens, out1, nullptr);
    xgemm2p<<<128, 512, 0, stream>>>(out1, W2x, b1, Xp);
    lstm_mx8<<<BB, 512, 0, stream>>>(Wsw2, Xp, lens, h2bf, h2f8);
    ce_kernel<<<NROWS / 64, 256, 0, stream>>>(h2f8, Wt8, obp, input_y, lens, out);
}

// Round 16
// 1664.273 us; speedup vs baseline: 1.2053x; 1.0246x over previous
//
#include <hip/hip_runtime.h>
#include <hip/hip_fp8.h>
#include <cmath>

#define SS 512
#define BB 32
#define EE 128
#define HH 256
#define VV 10000
#define NROWS (SS*BB)   // 16384
#define VPAD 10048
#define NT8 (VPAD/16)   // 628 fp8 B-tiles

typedef unsigned short ushort_t;
typedef unsigned char uchar_t;
typedef __attribute__((ext_vector_type(8))) short bf16x8;
typedef __attribute__((ext_vector_type(8))) int i32x8;
typedef __attribute__((ext_vector_type(4))) float f32x4;

#define MFMA(a,b,c)  __builtin_amdgcn_mfma_f32_16x16x32_bf16((a),(b),(c),0,0,0)
// fp8 x fp8, K=128, unit scales (E8M0 127 = 1.0) -> numerically plain fp8 matmul
#define MFMAS(a,b,c) __builtin_amdgcn_mfma_scale_f32_16x16x128_f8f6f4((a),(b),(c),0,0,0,0x7F7F7F7F,0,0x7F7F7F7F)

__device__ __forceinline__ ushort_t f2bf(float x) {
    unsigned u = __float_as_uint(x);
    u = (u + 0x7FFFu + ((u >> 16) & 1u)) >> 16;   // RNE
    return (ushort_t)u;
}
__device__ __forceinline__ float bf2f(ushort_t h) {
    return __uint_as_float(((unsigned)h) << 16);
}
__device__ __forceinline__ uchar_t f2fp8(float x) {
    __hip_fp8_e4m3 t(x);                           // OCP e4m3
    return (uchar_t)t.__x;
}
__device__ __forceinline__ float sigf(float x) { return 1.0f / (1.0f + __expf(-x)); }
__device__ __forceinline__ float tanhf_(float x) { return 1.0f - 2.0f / (__expf(2.0f * x) + 1.0f); }

// assemble a 32-B fp8 fragment from two 16-B halves 1024 B apart (LDS or global)
__device__ __forceinline__ i32x8 ldfrag(const uchar_t* base, int lane) {
    i32x8 r;
    ((uint4*)&r)[0] = *(const uint4*)(base + lane * 16);
    ((uint4*)&r)[1] = *(const uint4*)(base + 1024 + lane * 16);
    return r;
}

// ---------------- k0 x-part transpose: fp32 [128 k][1024 n] -> bf16 [1024 n][128 k] ----
__global__ __launch_bounds__(256)
void wtx(const float* __restrict__ src, ushort_t* __restrict__ dst)
{
    __shared__ float tile[64][65];
    const int tid = threadIdx.x;
    const int n0 = blockIdx.x * 64, k0_ = blockIdx.y * 64;
    for (int i = tid; i < 4096; i += 256) {
        const int kk = i >> 6, nn = i & 63;
        tile[kk][nn] = src[(size_t)(k0_ + kk) * 1024 + n0 + nn];
    }
    __syncthreads();
    for (int i = tid; i < 4096; i += 256) {
        const int nn = i >> 6, kk = i & 63;
        dst[(size_t)(n0 + nn) * 128 + k0_ + kk] = f2bf(tile[kk][nn]);
    }
}

// ---------------- MFMA zgemm: Z[m][1024] = bf16( emb[x[m]] @ k0x + b0 ) ----------------
// Grid (256, 4): 64 rows x 256 cols per block; 256 thr = 4 waves, wave w = m-tile w.
// A staged to LDS (gathered, bf16, 136-short stride); B frags from W1xT (ce-convention).
__global__ __launch_bounds__(256)
void zgemm_mf(const ushort_t* __restrict__ W1xT, const float* __restrict__ b0v,
              const float* __restrict__ emb, const int* __restrict__ idx,
              ushort_t* __restrict__ Zb)
{
    __shared__ ushort_t ash[64 * 136];
    const int tid = threadIdx.x;
    const int w = tid >> 6, lane = tid & 63;
    const int q = lane >> 4, n16 = lane & 15;
    const int m0 = blockIdx.x * 64;
    const int nbase = blockIdx.y * 256;

    for (int i = tid; i < 64 * 32; i += 256) {      // gather A: 64 rows x 128 k
        const int r_ = i >> 5, c4 = i & 31;
        const int m = m0 + r_;
        const int t = m >> 5, b = m & 31;
        const int id = idx[b * SS + t];
        const float4 v = ((const float4*)emb)[(size_t)id * 32 + c4];
        ushort_t o4[4] = { f2bf(v.x), f2bf(v.y), f2bf(v.z), f2bf(v.w) };
        *(uint2*)&ash[r_ * 136 + c4 * 4] = *(uint2*)o4;
    }
    __syncthreads();

    bf16x8 A[4];
#pragma unroll
    for (int kb = 0; kb < 4; kb++)
        A[kb] = *(const bf16x8*)&ash[(w * 16 + n16) * 136 + kb * 32 + q * 8];

#pragma unroll 1
    for (int nt = 0; nt < 16; nt++) {
        const int n = nbase + nt * 16 + n16;
        bf16x8 B[4];
#pragma unroll
        for (int kb = 0; kb < 4; kb++)
            B[kb] = *(const bf16x8*)&W1xT[(size_t)n * 128 + kb * 32 + q * 8];
        f32x4 C = (f32x4){0.f, 0.f, 0.f, 0.f};
#pragma unroll
        for (int kb = 0; kb < 4; kb++)
            C = MFMA(A[kb], B[kb], C);
        const float bv = b0v[n];
#pragma unroll
        for (int r = 0; r < 4; r++)
            Zb[(size_t)(m0 + w * 16 + q * 4 + r) * 1024 + n] = f2bf(C[r] + bv);
    }
}

// ---------------- h-part weights -> fp8 K=128 fragment layout (R12-validated) ----------
__global__ __launch_bounds__(256)
void wf8k128(const float* __restrict__ src, uchar_t* __restrict__ dst)
{
    const int nt = blockIdx.x;             // 0..63
    const int t = threadIdx.x;
    const int kk = t >> 7, h = (t >> 6) & 1, l = t & 63;
    const int q = l >> 4, n16 = l & 15;
    const int col = (nt >> 4) * 256 + (nt & 15) * 16 + n16;
    uchar_t v[16];
#pragma unroll
    for (int j = 0; j < 16; j++) {
        const int k = kk * 128 + q * 32 + h * 16 + j;
        v[j] = f2fp8(src[(size_t)k * 1024 + col]);
    }
    *(uint4*)&dst[(((size_t)(nt * 2 + kk) * 2 + h) * 64 + l) * 16] = *(uint4*)v;
}

// ---------------- out_W -> fp8 K=128 fragment layout, V padded (R14-validated) ---------
__global__ __launch_bounds__(256)
void wtf8(const float* __restrict__ W, uchar_t* __restrict__ dst)
{
    const int nt = blockIdx.x;             // 0..627
    const int t = threadIdx.x;
    const int kk = t >> 7, h = (t >> 6) & 1, l = t & 63;
    const int q = l >> 4, n16 = l & 15;
    const int col = nt * 16 + n16;
    uchar_t v[16];
#pragma unroll
    for (int j = 0; j < 16; j++) {
        const int k = kk * 128 + q * 32 + h * 16 + j;
        v[j] = (col < VV) ? f2fp8(W[(size_t)k * VV + col]) : (uchar_t)0;
    }
    *(uint4*)&dst[(((size_t)(nt * 2 + kk) * 2 + h) * 64 + l) * 16] = *(uint4*)v;
}

// ---------------- fp32[256 x 1024] -> bf16 [1024][256] transpose (R6-validated) --------
__global__ __launch_bounds__(256)
void wtgen(const float* __restrict__ src, ushort_t* __restrict__ dst)
{
    __shared__ float tile[64][65];
    const int tid = threadIdx.x;
    const int n0 = blockIdx.x * 64, k0 = blockIdx.y * 64;
    for (int i = tid; i < 4096; i += 256) {
        const int kk = i >> 6, nn = i & 63;
        tile[kk][nn] = src[(size_t)(k0 + kk) * 1024 + n0 + nn];
    }
    __syncthreads();
    for (int i = tid; i < 4096; i += 256) {
        const int nn = i >> 6, kk = i & 63;
        dst[(size_t)(n0 + nn) * 256 + k0 + kk] = f2bf(tile[kk][nn]);
    }
}

__global__ __launch_bounds__(256)
void obset_kernel(const float* __restrict__ ob, float* __restrict__ obp)
{
    const int v = blockIdx.x * 256 + threadIdx.x;
    if (v < VPAD) obp[v] = (v < VV) ? ob[v] : -INFINITY;
}

// ---------------- batch-parallel LSTM, K=128 fp8, 8 waves, 4V/3L/1S ----------------
// 1 block / batch element; 512 thr = 8 waves (2/SIMD). Wave w owns units
// [w*32,(w+1)*32); lane (q,n16) owns unit w*32+(q>>1)*16+n16 (dup lanes benign).
// Tile (g,j): nt = g*16 + w*2 + j. Residency per wave (8 tiles):
//   VGPR 4 {(g,0) g=0..3} = 64 regs   (R15 PM: LDS port was floor at 4L)
//   LDS  3 {(0,1),(1,1),(2,1)} = 12 KB/wave (96 KB/CU)
//   stream 1 {(3,1)} warm L2
// h fp8 double-buffered LDS; ONE barrier/step; uniform early-exit (R9-validated).
__global__ __launch_bounds__(512, 2)
void lstm_mx8(const uchar_t* __restrict__ Wsw, const ushort_t* __restrict__ zin,
              const int* __restrict__ lens, ushort_t* __restrict__ outp,
              uchar_t* __restrict__ hf8)
{
    __shared__ uchar_t Bl[98304];      // 8 waves x 3 tiles x 4 KB
    __shared__ uchar_t h8[2][256];
    const int tid = threadIdx.x;
    const int w = tid >> 6, lane = tid & 63;
    const int q = lane >> 4, n16 = lane & 15;
    const int b = blockIdx.x;
    const int len = lens[b];
    const int jown = q >> 1;
    const int unit = w * 32 + jown * 16 + n16;

    // LDS staging: wave-local tiles {(0,1),(1,1),(2,1)}
#pragma unroll
    for (int li = 0; li < 3; li++) {
        const int nt = li * 16 + w * 2 + 1;
#pragma unroll
        for (int fh = 0; fh < 4; fh++) {
            const size_t s = (((size_t)nt * 4 + fh) * 64 + lane) * 16;
            const size_t d = (((size_t)(w * 3 + li) * 4 + fh) * 64 + lane) * 16;
            *(uint4*)&Bl[d] = *(const uint4*)&Wsw[s];
        }
    }
    // VGPR tiles {(g,0)}
    i32x8 Bv[4][2];
#pragma unroll
    for (int g = 0; g < 4; g++) {
        const int nt = g * 16 + w * 2;
#pragma unroll
        for (int kk = 0; kk < 2; kk++)
            Bv[g][kk] = ldfrag(&Wsw[(size_t)nt * 4096 + kk * 2048], lane);
    }
    if (tid < 256) { h8[0][tid] = 0; h8[1][tid] = 0; }
    float c = 0.f;
    __syncthreads();

    const uchar_t* Lb0 = &Bl[(size_t)(w * 3) * 4096];   // wave's LDS region

    for (int t = 0; t < SS; t++) {
        if (t >= len) {                // uniform: zero remaining rows, done
            uint4 zz; zz.x = zz.y = zz.z = zz.w = 0u;
            const int nseg = (SS - t) * 32;
            for (int i = tid; i < nseg; i += 512) {
                const int tt = t + (i >> 5), seg = i & 31;
                *(uint4*)&outp[((size_t)tt * 32 + b) * 256 + seg * 8] = zz;
            }
            if (hf8) {
                const int nseg8 = (SS - t) * 16;
                for (int i = tid; i < nseg8; i += 512) {
                    const int tt = t + (i >> 4), seg = i & 15;
                    *(uint4*)&hf8[((size_t)tt * 32 + b) * 256 + seg * 16] = zz;
                }
            }
            break;
        }
        const size_t row = (size_t)t * 32 + b;
        // streamed tile (3,1) — issue first, consume last
        i32x8 St[2];
        {
            const int nt = 3 * 16 + w * 2 + 1;
#pragma unroll
            for (int kk = 0; kk < 2; kk++)
                St[kk] = ldfrag(&Wsw[(size_t)nt * 4096 + kk * 2048], lane);
        }
        ushort_t z4[4];
#pragma unroll
        for (int g = 0; g < 4; g++) z4[g] = zin[row * 1024 + g * 256 + unit];

        const int rd = t & 1, wr = rd ^ 1;
        i32x8 Af0, Af1;                // A: rows identical (quad-broadcast from h8)
        ((uint4*)&Af0)[0] = *(const uint4*)&h8[rd][q * 32];
        ((uint4*)&Af0)[1] = *(const uint4*)&h8[rd][q * 32 + 16];
        ((uint4*)&Af1)[0] = *(const uint4*)&h8[rd][128 + q * 32];
        ((uint4*)&Af1)[1] = *(const uint4*)&h8[rd][128 + q * 32 + 16];

        float gvv[4];
#pragma unroll
        for (int g = 0; g < 4; g++) {
            f32x4 C0 = (f32x4){0.f,0.f,0.f,0.f}, C1 = (f32x4){0.f,0.f,0.f,0.f};
            C0 = MFMAS(Af0, Bv[g][0], C0);         // j=0 from VGPR
            C0 = MFMAS(Af1, Bv[g][1], C0);
            if (g < 3) {               // (g,1) from LDS li = g
                const uchar_t* p = Lb0 + (size_t)g * 4096;
                C1 = MFMAS(Af0, ldfrag(p, lane), C1);
                C1 = MFMAS(Af1, ldfrag(p + 2048, lane), C1);
            } else {                   // (3,1) streamed
                C1 = MFMAS(Af0, St[0], C1);
                C1 = MFMAS(Af1, St[1], C1);
            }
            gvv[g] = jown ? C1[0] : C0[0];   // rows identical; col = n16 of owned tile
        }
        {
            const float zi = bf2f(z4[0]) + gvv[0];
            const float zg = bf2f(z4[1]) + gvv[1];
            const float zf = bf2f(z4[2]) + gvv[2];
            const float zo = bf2f(z4[3]) + gvv[3];
            const float cn = sigf(zf + 1.0f) * c + sigf(zi) * tanhf_(zg);
            const float hn = sigf(zo) * tanhf_(cn);
            c = cn;
            const uchar_t h8v = f2fp8(hn);
            h8[wr][unit] = h8v;                       // dup lanes write same value
            outp[row * 256 + unit] = f2bf(hn);
            if (hf8) hf8[row * 256 + unit] = h8v;
        }
        __syncthreads();               // h8[wr] complete + visible for next step
    }
}

// ---------------- layer-2 x-part GEMM + b1, plain bf16 out (R9-validated) ----------------
__global__ __launch_bounds__(512, 2)
void xgemm2p(const ushort_t* __restrict__ out1, const ushort_t* __restrict__ W2x,
             const float* __restrict__ b1v, ushort_t* __restrict__ Xp)
{
    const int tid = threadIdx.x;
    const int w = tid >> 6, lane = tid & 63;
    const int q = lane >> 4, n16 = lane & 15;
    const int m0 = blockIdx.x * 128;           // 4 timesteps x 32 batch
#pragma unroll 1
    for (int i = 0; i < 8; i++) {
        const int n = (w * 8 + i) * 16 + n16;
        bf16x8 Bfr[8];
#pragma unroll
        for (int kb = 0; kb < 8; kb++)
            Bfr[kb] = *(const bf16x8*)&W2x[(size_t)n * 256 + kb * 32 + q * 8];
        const float bval = b1v[n];
        f32x4 Cc[8];
#pragma unroll
        for (int mt = 0; mt < 8; mt++) {
            Cc[mt] = (f32x4){0.f, 0.f, 0.f, 0.f};
            bf16x8 Af[8];
#pragma unroll
            for (int kb = 0; kb < 8; kb++)
                Af[kb] = *(const bf16x8*)&out1[(size_t)(m0 + mt * 16 + n16) * 256 + kb * 32 + q * 8];
#pragma unroll
            for (int kb = 0; kb < 8; kb++)
                Cc[mt] = MFMA(Af[kb], Bfr[kb], Cc[mt]);
        }
#pragma unroll
        for (int mt = 0; mt < 8; mt++)
#pragma unroll
            for (int r = 0; r < 4; r++) {
                const int rrow = m0 + mt * 16 + q * 4 + r;
                Xp[(size_t)rrow * 1024 + n] = f2bf(Cc[mt][r] + bval);
            }
    }
}

// ---------------- fp8 K=128 fused projection + CE (R14-validated) ----------------
__global__ __launch_bounds__(256, 1)
void ce_kernel(const uchar_t* __restrict__ hf8, const uchar_t* __restrict__ Wt8,
               const float* __restrict__ obp, const int* __restrict__ y,
               const int* __restrict__ lens, float* __restrict__ out)
{
    __shared__ float lsw[4][64];
    __shared__ float tgt64[64];
    const int tid = threadIdx.x;
    const int w = tid >> 6, lane = tid & 63;
    const int q = lane >> 4, n16 = lane & 15;
    const int m0 = blockIdx.x * 64;

    if (tid < 64) tgt64[tid] = 0.f;

    i32x8 A8[4][2];
#pragma unroll
    for (int mt = 0; mt < 4; mt++) {
        const size_t rbase = (size_t)(m0 + mt * 16 + n16) * 256;
#pragma unroll
        for (int kk = 0; kk < 2; kk++) {
            ((uint4*)&A8[mt][kk])[0] = *(const uint4*)&hf8[rbase + kk * 128 + q * 32];
            ((uint4*)&A8[mt][kk])[1] = *(const uint4*)&hf8[rbase + kk * 128 + q * 32 + 16];
        }
    }
    int yv[16];
#pragma unroll
    for (int mt = 0; mt < 4; mt++)
#pragma unroll
        for (int r = 0; r < 4; r++) {
            const int m = m0 + mt * 16 + q * 4 + r;
            yv[mt * 4 + r] = y[(m & 31) * SS + (m >> 5)];
        }
    float lsum[16];
#pragma unroll
    for (int i = 0; i < 16; i++) lsum[i] = 0.f;
    __syncthreads();                   // tgt64 init visible

    for (int tile = 0; tile < 157; tile++) {
        const int nt = w * 157 + tile;
        const int n = nt * 16 + n16;
        const i32x8 B0 = ldfrag(&Wt8[(size_t)(nt * 2 + 0) * 2048], lane);
        const i32x8 B1 = ldfrag(&Wt8[(size_t)(nt * 2 + 1) * 2048], lane);
        const float obv = obp[n];
        f32x4 C[4];
#pragma unroll
        for (int mt = 0; mt < 4; mt++) {
            C[mt] = (f32x4){0.f, 0.f, 0.f, 0.f};
            C[mt] = MFMAS(A8[mt][0], B0, C[mt]);
            C[mt] = MFMAS(A8[mt][1], B1, C[mt]);
        }
#pragma unroll
        for (int mt = 0; mt < 4; mt++)
#pragma unroll
            for (int r = 0; r < 4; r++) {
                const float sc = C[mt][r] + obv;     // -inf on padded cols
                if (n == yv[mt * 4 + r]) tgt64[mt * 16 + q * 4 + r] = sc;
                lsum[mt * 4 + r] += __expf(sc - 16.0f);
            }
    }
#pragma unroll
    for (int i = 0; i < 16; i++) {
        float v = lsum[i];
        v += __shfl_xor(v, 1, 16); v += __shfl_xor(v, 2, 16);
        v += __shfl_xor(v, 4, 16); v += __shfl_xor(v, 8, 16);
        lsum[i] = v;
    }
    if (n16 == 0)
#pragma unroll
        for (int i = 0; i < 16; i++)
            lsw[w][(i >> 2) * 16 + q * 4 + (i & 3)] = lsum[i];
    __syncthreads();

    if (tid < 64) {
        const float l = lsw[0][tid] + lsw[1][tid] + lsw[2][tid] + lsw[3][tid];
        const float lse = 16.0f + __logf(l);
        const int m = m0 + tid;
        const int tt = m >> 5, bb = m & 31;
        const int yvv = y[bb * SS + tt];
        float local = (yvv != 0) ? (lse - tgt64[tid]) / (32.0f * (float)lens[bb]) : 0.f;
        for (int off = 1; off < 64; off <<= 1) local += __shfl_xor(local, off, 64);
        if (tid == 0) atomicAdd(out, local);
    }
}

extern "C" void kernel_launch(void* const* d_in, const int* in_sizes, int n_in,
                              void* d_out, int out_size, void* d_ws, size_t ws_size,
                              hipStream_t stream)
{
    const int*   input_x = (const int*)  d_in[0];
    const int*   input_y = (const int*)  d_in[1];
    const int*   lens    = (const int*)  d_in[2];
    const float* emb_W   = (const float*)d_in[3];
    const float* k0      = (const float*)d_in[4];
    const float* b0      = (const float*)d_in[5];
    const float* k1      = (const float*)d_in[6];
    const float* b1      = (const float*)d_in[7];
    const float* out_W   = (const float*)d_in[8];
    const float* out_b   = (const float*)d_in[9];
    float* out = (float*)d_out;

    char* p = (char*)d_ws;
    ushort_t* Zb   = (ushort_t*)p;  p += (size_t)NROWS * 1024 * 2;    // 33.55 MB
    ushort_t* Xp   = (ushort_t*)p;  p += (size_t)NROWS * 1024 * 2;    // 33.55 MB
    ushort_t* out1 = (ushort_t*)p;  p += (size_t)NROWS * 256 * 2;     // 8.39 MB
    ushort_t* h2bf = (ushort_t*)p;  p += (size_t)NROWS * 256 * 2;     // 8.39 MB
    uchar_t*  h2f8 = (uchar_t*)p;   p += (size_t)NROWS * 256;         // 4.19 MB
    uchar_t*  Wsw1 = (uchar_t*)p;   p += (size_t)1024 * 256;          // 256 KB
    uchar_t*  Wsw2 = (uchar_t*)p;   p += (size_t)1024 * 256;          // 256 KB
    ushort_t* W2x  = (ushort_t*)p;  p += (size_t)1024 * 256 * 2;      // 512 KB
    ushort_t* W1xT = (ushort_t*)p;  p += (size_t)1024 * 128 * 2;      // 256 KB
    uchar_t*  Wt8  = (uchar_t*)p;   p += (size_t)NT8 * 4096;          // 2.57 MB
    float*    obp  = (float*)p;     p += (size_t)VPAD * 4;

    hipMemsetAsync(d_out, 0, sizeof(float), stream);

    wtx<<<dim3(16, 2), 256, 0, stream>>>(k0, W1xT);                  // k0 x-part bf16^T
    zgemm_mf<<<dim3(256, 4), 256, 0, stream>>>(W1xT, b0, emb_W, input_x, Zb);
    wf8k128<<<64, 256, 0, stream>>>(k0 + (size_t)EE * 1024, Wsw1);   // L1 h-part fp8 K128
    wf8k128<<<64, 256, 0, stream>>>(k1 + (size_t)HH * 1024, Wsw2);   // L2 h-part fp8 K128
    wtgen<<<dim3(16, 4), 256, 0, stream>>>(k1, W2x);                 // L2 x-part bf16
    wtf8<<<NT8, 256, 0, stream>>>(out_W, Wt8);                       // out_W fp8 K128
    obset_kernel<<<(VPAD + 255) / 256, 256, 0, stream>>>(out_b, obp);

    lstm_mx8<<<BB, 512, 0, stream>>>(Wsw1, Zb, lens, out1, nullptr);
    xgemm2p<<<128, 512, 0, stream>>>(out1, W2x, b1, Xp);
    lstm_mx8<<<BB, 512, 0, stream>>>(Wsw2, Xp, lens, h2bf, h2f8);
    ce_kernel<<<NROWS / 64, 256, 0, stream>>>(h2f8, Wt8, obp, input_y, lens, out);
}